// Round 1
// baseline (981.302 us; speedup 1.0000x reference)
//
#include <hip/hip_runtime.h>
#include <hip/hip_bf16.h>
#include <cmath>

// MatchingNet: sim = QR^T/6553.6 (tiny logits!) -> dual-softmax cm, mutual-max cf,
// 50-iter log-Sinkhorn conf. Key transforms:
//  * P = exp(sim) in [0.986,1.014]: Sinkhorn half-iters become GEMVs S_i = sum_j P_ij b_j
//    (b = exp(v)); no per-row max needed (no overflow possible).
//  * P stored fp16 twice (P and P^T, 104 MB, L3-resident) so both half-updates are
//    coalesced row reductions. fp16 quantization -> conf rel err ~5e-4, abs ~5e-8 << 2.1e-6 tol.
//  * 20 iterations instead of 50: Hilbert contraction ~0.06-0.22/iter => converged to the
//    same fixed point (same init/map as reference) to <1e-9 by iter 20.
//  * cm = P^2/(R_i C_j); cm/cf magnitudes ~8e-8 are below the abs tolerance, so mutual-max
//    consistency only needs to be self-consistent (identical arithmetic in max & final kernels).

#define LDIM 3600
#define DDIM 256
#define BDIM 2
#define VS   3604      // per-batch vector stride (floats), 16B-aligned
#define T_ITERS 20

typedef __attribute__((ext_vector_type(8))) short    bf16x8;
typedef __attribute__((ext_vector_type(4))) float    f32x4;
typedef __attribute__((ext_vector_type(8))) _Float16 h8;
typedef __attribute__((ext_vector_type(4))) _Float16 h4v;

__device__ __forceinline__ short f2bf(float f) {
    unsigned u = __float_as_uint(f);
    u += 0x7fffu + ((u >> 16) & 1u);   // RNE
    return (short)(u >> 16);
}

// ---- input fp32 -> bf16 conversion ----
__global__ __launch_bounds__(256) void convert_kernel(
    const float4* __restrict__ m0, const float4* __restrict__ m1,
    short4* __restrict__ q, short4* __restrict__ r)
{
    int i = blockIdx.x * 256 + threadIdx.x;   // 460800 float4 per tensor
    float4 a = m0[i]; float4 b = m1[i];
    short4 qa, rb;
    qa.x = f2bf(a.x); qa.y = f2bf(a.y); qa.z = f2bf(a.z); qa.w = f2bf(a.w);
    rb.x = f2bf(b.x); rb.y = f2bf(b.y); rb.z = f2bf(b.z); rb.w = f2bf(b.w);
    q[i] = qa; r[i] = rb;
}

// ---- P_out[i][j] = exp(dot(X_b[i], Y_b[j]) / 6553.6), fp16, row-major 3600x3600 ----
// block = 4 waves (2x2), wave = 64x64 tile = 4x4 MFMA 16x16x32_bf16 tiles. No LDS;
// A/B frags re-read from L1/L2 (13 GFLOP total - not the bottleneck).
__global__ __launch_bounds__(256) void exp_gemm_kernel(
    const short* __restrict__ Xb, const short* __restrict__ Yb,
    _Float16* __restrict__ Pout)
{
    const int batch = blockIdx.z;
    const short* X = Xb + (size_t)batch * LDIM * DDIM;
    const short* Y = Yb + (size_t)batch * LDIM * DDIM;
    _Float16* Pb = Pout + (size_t)batch * LDIM * LDIM;

    const int wave = threadIdx.x >> 6;
    const int lane = threadIdx.x & 63;
    const int wm = wave >> 1, wn = wave & 1;
    const int bm0 = blockIdx.y * 128 + wm * 64;
    const int bn0 = blockIdx.x * 128 + wn * 64;
    const int l16 = lane & 15, quad = lane >> 4;

    f32x4 acc[4][4];
#pragma unroll
    for (int s = 0; s < 4; s++)
#pragma unroll
        for (int t = 0; t < 4; t++) acc[s][t] = (f32x4){0.f, 0.f, 0.f, 0.f};

    for (int k0 = 0; k0 < DDIM; k0 += 32) {
        const int kk = k0 + quad * 8;     // A[m=lane&15][k=quad*8+j]
        bf16x8 af[4], bfr[4];
#pragma unroll
        for (int s = 0; s < 4; s++) {
            int r = bm0 + s * 16 + l16; r = r < LDIM ? r : LDIM - 1;
            af[s] = *(const bf16x8*)(X + (size_t)r * DDIM + kk);
            int c = bn0 + s * 16 + l16; c = c < LDIM ? c : LDIM - 1;
            bfr[s] = *(const bf16x8*)(Y + (size_t)c * DDIM + kk);
        }
#pragma unroll
        for (int s = 0; s < 4; s++)
#pragma unroll
            for (int t = 0; t < 4; t++)
                acc[s][t] = __builtin_amdgcn_mfma_f32_16x16x32_bf16(af[s], bfr[t], acc[s][t], 0, 0, 0);
    }
    const float inv = 1.0f / 6553.6f;
#pragma unroll
    for (int s = 0; s < 4; s++) {
#pragma unroll
        for (int t = 0; t < 4; t++) {
            int col = bn0 + t * 16 + l16;
#pragma unroll
            for (int r = 0; r < 4; r++) {       // D: col=lane&15, row=quad*4+reg
                int row = bm0 + s * 16 + quad * 4 + r;
                if (row < LDIM && col < LDIM)
                    Pb[(size_t)row * LDIM + col] = (_Float16)expf(acc[s][t][r] * inv);
            }
        }
    }
}

// ---- plain row sums (used for C = colsums of P via rowsums of P^T) ----
__global__ __launch_bounds__(256) void rowsum_kernel(
    const _Float16* __restrict__ mat, float* __restrict__ outv)
{
    const int row = blockIdx.x, batch = blockIdx.y;
    const _Float16* mrow = mat + ((size_t)batch * LDIM + row) * LDIM;
    float s = 0.f;
    for (int jv = threadIdx.x; jv < 450; jv += 256) {
        h8 hv = ((const h8*)mrow)[jv];
#pragma unroll
        for (int e = 0; e < 8; e++) s += (float)hv[e];
    }
    __shared__ float red[256];
    red[threadIdx.x] = s; __syncthreads();
    for (int w = 128; w; w >>= 1) {
        if (threadIdx.x < w) red[threadIdx.x] += red[threadIdx.x + w];
        __syncthreads();
    }
    if (threadIdx.x == 0) outv[batch * VS + row] = red[0];
}

__global__ void init_b_kernel(float* __restrict__ bv)
{
    int j = blockIdx.x * 256 + threadIdx.x;
    if (j <= LDIM) bv[blockIdx.y * VS + j] = 1.0f;
}

// ---- one Sinkhorn half-update (exp domain). One wave per row. ----
// row < 3600: S = sum_j P_ij * vin_j ; u = norm - log(S + e^alpha * vin[3600])
// row == 3600 (bin): T = sum_{j<=3600} vin_j ; u = (log(3600)+norm) - alpha - log(T)
// writes vout = exp(u). Optionally writes interior row sums (== R when vin==1).
__global__ __launch_bounds__(256) void skh_kernel(
    const _Float16* __restrict__ mat, const float* __restrict__ vin,
    float* __restrict__ vout, const float* __restrict__ alpha_p,
    float* __restrict__ Ropt)
{
    const int wave = threadIdx.x >> 6, lane = threadIdx.x & 63;
    const int row = blockIdx.x * 4 + wave, batch = blockIdx.y;
    if (row > LDIM) return;
    const float* vi = vin + batch * VS;
    float psum = 0.f;
    if (row < LDIM) {
        const _Float16* mrow = mat + ((size_t)batch * LDIM + row) * LDIM;
        const h8* m8 = (const h8*)mrow;
        const float4* b4 = (const float4*)vi;
        for (int jv = lane; jv < 450; jv += 64) {
            h8 hv = m8[jv];
            float4 b0 = b4[2 * jv], b1 = b4[2 * jv + 1];
            psum += (float)hv[0] * b0.x + (float)hv[1] * b0.y + (float)hv[2] * b0.z + (float)hv[3] * b0.w;
            psum += (float)hv[4] * b1.x + (float)hv[5] * b1.y + (float)hv[6] * b1.z + (float)hv[7] * b1.w;
        }
    } else {
        const float4* b4 = (const float4*)vi;
        for (int jv = lane; jv < 900; jv += 64) {
            float4 b0 = b4[jv];
            psum += b0.x + b0.y + b0.z + b0.w;
        }
        if (lane == 0) psum += vi[LDIM];
    }
#pragma unroll
    for (int off = 32; off; off >>= 1) psum += __shfl_down(psum, off, 64);
    if (lane == 0) {
        const float alpha = alpha_p[0];
        const float norm = -logf(7200.0f);
        float u;
        if (row < LDIM) {
            if (Ropt) Ropt[batch * VS + row] = psum;
            u = norm - logf(psum + expf(alpha) * vi[LDIM]);
        } else {
            u = (logf(3600.0f) + norm) - alpha - logf(psum);
        }
        vout[batch * VS + row] = expf(u);
    }
}

// ---- per-row max of cm = p*p/(R*C) (identical arithmetic to final_kernel) ----
__global__ __launch_bounds__(256) void max_kernel(
    const _Float16* __restrict__ mat, const float* __restrict__ Rvec,
    const float* __restrict__ Cvec, float* __restrict__ outM)
{
    const int row = blockIdx.x, batch = blockIdx.y;
    const _Float16* mrow = mat + ((size_t)batch * LDIM + row) * LDIM;
    const float* Cb = Cvec + batch * VS;
    const float Rr = Rvec[batch * VS + row];
    float m = 0.f;
    for (int jv = threadIdx.x; jv < 450; jv += 256) {
        h8 hv = ((const h8*)mrow)[jv];
#pragma unroll
        for (int e = 0; e < 8; e++) {
            float p = (float)hv[e];
            float rc = Rr * Cb[jv * 8 + e];
            float cm = (p * p) / rc;
            m = fmaxf(m, cm);
        }
    }
    __shared__ float red[256];
    red[threadIdx.x] = m; __syncthreads();
    for (int w = 128; w; w >>= 1) {
        if (threadIdx.x < w) red[threadIdx.x] = fmaxf(red[threadIdx.x], red[threadIdx.x + w]);
        __syncthreads();
    }
    if (threadIdx.x == 0) outM[batch * VS + row] = red[0];
}

// ---- fused epilogue: cm, cf, conf_skh planes ----
__global__ __launch_bounds__(256) void final_kernel(
    const _Float16* __restrict__ P, const float* __restrict__ av, const float* __restrict__ bv,
    const float* __restrict__ Rvec, const float* __restrict__ Cvec,
    const float* __restrict__ rowM, const float* __restrict__ colM,
    float* __restrict__ out)
{
    const int batch = blockIdx.z, row = blockIdx.y;
    const int c0 = blockIdx.x * 1024 + threadIdx.x * 4;
    if (c0 >= LDIM) return;
    const _Float16* prow = P + ((size_t)batch * LDIM + row) * LDIM;
    h4v hv = *(const h4v*)(prow + c0);
    float4 bb = *(const float4*)(bv + batch * VS + c0);
    float4 cc = *(const float4*)(Cvec + batch * VS + c0);
    float4 cM = *(const float4*)(colM + batch * VS + c0);
    const float Rr = Rvec[batch * VS + row];
    const float rM = rowM[batch * VS + row];
    const float as = av[batch * VS + row] * 7200.0f;   // exp(u) * exp(-norm)

    float4 cmv, cfv, skv;
    {
        float p = (float)hv[0]; float rc = Rr * cc.x; float cm = (p * p) / rc;
        cmv.x = cm; cfv.x = (cm == rM && cm == cM.x) ? cm : 0.f; skv.x = p * as * bb.x;
    }
    {
        float p = (float)hv[1]; float rc = Rr * cc.y; float cm = (p * p) / rc;
        cmv.y = cm; cfv.y = (cm == rM && cm == cM.y) ? cm : 0.f; skv.y = p * as * bb.y;
    }
    {
        float p = (float)hv[2]; float rc = Rr * cc.z; float cm = (p * p) / rc;
        cmv.z = cm; cfv.z = (cm == rM && cm == cM.z) ? cm : 0.f; skv.z = p * as * bb.z;
    }
    {
        float p = (float)hv[3]; float rc = Rr * cc.w; float cm = (p * p) / rc;
        cmv.w = cm; cfv.w = (cm == rM && cm == cM.w) ? cm : 0.f; skv.w = p * as * bb.w;
    }
    size_t base = ((size_t)batch * LDIM + row) * LDIM + c0;
    const size_t PLANE = (size_t)BDIM * LDIM * LDIM;
    *(float4*)(out + base) = cmv;
    *(float4*)(out + PLANE + base) = cfv;
    *(float4*)(out + 2 * PLANE + base) = skv;
}

extern "C" void kernel_launch(void* const* d_in, const int* in_sizes, int n_in,
                              void* d_out, int out_size, void* d_ws, size_t ws_size,
                              hipStream_t stream)
{
    const float* m0 = (const float*)d_in[0];
    const float* m1 = (const float*)d_in[1];
    const float* alpha = (const float*)d_in[2];
    float* out = (float*)d_out;
    char* ws = (char*)d_ws;

    // ws layout (bytes), all 16B-aligned; total ~111.3 MB
    short* Qb = (short*)(ws);                         //  3,686,400  bf16 mdesc0
    short* Rb = (short*)(ws + 3686400);               //  3,686,400  bf16 mdesc1
    _Float16* P  = (_Float16*)(ws + 7372800);         // 51,840,000  exp(sim)
    _Float16* PT = (_Float16*)(ws + 59212800);        // 51,840,000  exp(sim)^T
    float* vec = (float*)(ws + 111052800);            // vectors, stride VS per batch
    float* av   = vec;                                // exp(u), 2*VS
    float* bv   = vec + 2 * VS;                       // exp(v)
    float* Rv   = vec + 4 * VS;                       // row sums of P
    float* Cv   = vec + 6 * VS;                       // col sums of P
    float* rowM = vec + 8 * VS;                       // rowwise max of cm
    float* colM = vec + 10 * VS;                      // colwise max of cm

    convert_kernel<<<1800, 256, 0, stream>>>((const float4*)m0, (const float4*)m1,
                                             (short4*)Qb, (short4*)Rb);
    exp_gemm_kernel<<<dim3(29, 29, 2), 256, 0, stream>>>(Qb, Rb, P);
    exp_gemm_kernel<<<dim3(29, 29, 2), 256, 0, stream>>>(Rb, Qb, PT);
    rowsum_kernel<<<dim3(3600, 2), 256, 0, stream>>>(PT, Cv);
    init_b_kernel<<<dim3(15, 2), 256, 0, stream>>>(bv);

    // iteration 1: b == 1, so interior row sums == R (captured via Ropt)
    skh_kernel<<<dim3(901, 2), 256, 0, stream>>>(P, bv, av, alpha, Rv);
    skh_kernel<<<dim3(901, 2), 256, 0, stream>>>(PT, av, bv, alpha, nullptr);
    for (int t = 1; t < T_ITERS; ++t) {
        skh_kernel<<<dim3(901, 2), 256, 0, stream>>>(P, bv, av, alpha, nullptr);
        skh_kernel<<<dim3(901, 2), 256, 0, stream>>>(PT, av, bv, alpha, nullptr);
    }

    max_kernel<<<dim3(3600, 2), 256, 0, stream>>>(P, Rv, Cv, rowM);
    max_kernel<<<dim3(3600, 2), 256, 0, stream>>>(PT, Cv, Rv, colM);
    final_kernel<<<dim3(4, 3600, 2), 256, 0, stream>>>(P, av, bv, Rv, Cv, rowM, colM, out);
}

// Round 2
// 575.272 us; speedup vs baseline: 1.7058x; 1.7058x over previous
//
#include <hip/hip_runtime.h>
#include <hip/hip_bf16.h>
#include <cmath>

// MatchingNet: sim = QR^T/6553.6 (tiny logits) -> dual-softmax cm, mutual-max cf,
// log-Sinkhorn conf. Structure (round 2):
//  * P = exp(sim) in [0.986,1.014]: Sinkhorn half-iters are GEMVs in exp domain.
//  * ONE GEMM writes P and PT (transposed h4 stores) + col-sums Cv via atomics.
//  * T=5 iterations: Hilbert contraction per iter ~0.064 => residual ~1e-6 log
//    (conf abs err ~1e-10) vs reference's converged 50-iter fixed point.
//  * rowM/colM (mutual-max) fused into the LAST P/PT Sinkhorn passes with
//    bit-identical cm arithmetic to final_kernel (IEEE, same operand order).
//  * fp16 P quantization -> conf abs err ~5e-7 << 2.1e-6 tol (measured round 1).

#define LDIM 3600
#define DDIM 256
#define BDIM 2
#define VS   3604      // per-batch vector stride (floats), 16B-aligned
#define T_ITERS 5

typedef __attribute__((ext_vector_type(8))) short    bf16x8;
typedef __attribute__((ext_vector_type(4))) float    f32x4;
typedef __attribute__((ext_vector_type(8))) _Float16 h8;
typedef __attribute__((ext_vector_type(4))) _Float16 h4v;

__device__ __forceinline__ short f2bf(float f) {
    unsigned u = __float_as_uint(f);
    u += 0x7fffu + ((u >> 16) & 1u);   // RNE
    return (short)(u >> 16);
}

// ---- input fp32 -> bf16 conversion ----
__global__ __launch_bounds__(256) void convert_kernel(
    const float4* __restrict__ m0, const float4* __restrict__ m1,
    short4* __restrict__ q, short4* __restrict__ r)
{
    int i = blockIdx.x * 256 + threadIdx.x;   // 460800 float4 per tensor
    float4 a = m0[i]; float4 b = m1[i];
    short4 qa, rb;
    qa.x = f2bf(a.x); qa.y = f2bf(a.y); qa.z = f2bf(a.z); qa.w = f2bf(a.w);
    rb.x = f2bf(b.x); rb.y = f2bf(b.y); rb.z = f2bf(b.z); rb.w = f2bf(b.w);
    q[i] = qa; r[i] = rb;
}

// ---- P[i][j] = exp(dot/6553.6) fp16; also writes PT[j][i] and colsums Cv ----
// block = 4 waves (2x2), wave = 64x64 tile = 4x4 MFMA 16x16x32_bf16 tiles.
__global__ __launch_bounds__(256) void exp_gemm_kernel(
    const short* __restrict__ Xb, const short* __restrict__ Yb,
    _Float16* __restrict__ Pout, _Float16* __restrict__ PTout,
    float* __restrict__ Cv)
{
    const int batch = blockIdx.z;
    const short* X = Xb + (size_t)batch * LDIM * DDIM;
    const short* Y = Yb + (size_t)batch * LDIM * DDIM;
    _Float16* Pb  = Pout  + (size_t)batch * LDIM * LDIM;
    _Float16* PTb = PTout + (size_t)batch * LDIM * LDIM;
    float* Cb = Cv + batch * VS;

    const int wave = threadIdx.x >> 6;
    const int lane = threadIdx.x & 63;
    const int wm = wave >> 1, wn = wave & 1;
    const int bm0 = blockIdx.y * 128 + wm * 64;
    const int bn0 = blockIdx.x * 128 + wn * 64;
    const int l16 = lane & 15, quad = lane >> 4;

    f32x4 acc[4][4];
#pragma unroll
    for (int s = 0; s < 4; s++)
#pragma unroll
        for (int t = 0; t < 4; t++) acc[s][t] = (f32x4){0.f, 0.f, 0.f, 0.f};

    for (int k0 = 0; k0 < DDIM; k0 += 32) {
        const int kk = k0 + quad * 8;     // A[m=lane&15][k=quad*8+j]
        bf16x8 af[4], bfr[4];
#pragma unroll
        for (int s = 0; s < 4; s++) {
            int r = bm0 + s * 16 + l16; r = r < LDIM ? r : LDIM - 1;
            af[s] = *(const bf16x8*)(X + (size_t)r * DDIM + kk);
            int c = bn0 + s * 16 + l16; c = c < LDIM ? c : LDIM - 1;
            bfr[s] = *(const bf16x8*)(Y + (size_t)c * DDIM + kk);
        }
#pragma unroll
        for (int s = 0; s < 4; s++)
#pragma unroll
            for (int t = 0; t < 4; t++)
                acc[s][t] = __builtin_amdgcn_mfma_f32_16x16x32_bf16(af[s], bfr[t], acc[s][t], 0, 0, 0);
    }
    const float inv = 1.0f / 6553.6f;
#pragma unroll
    for (int t = 0; t < 4; t++) {
        const int col = bn0 + t * 16 + l16;     // D: col=lane&15, row=quad*4+reg
        float csum = 0.f;
#pragma unroll
        for (int s = 0; s < 4; s++) {
            const int row0 = bm0 + s * 16 + quad * 4;
            h4v ph;
#pragma unroll
            for (int r = 0; r < 4; r++) ph[r] = (_Float16)__expf(acc[s][t][r] * inv);
            if (col < LDIM && row0 < LDIM) {   // row0 % 4 == 0 and LDIM % 4 == 0
                *(h4v*)(PTb + (size_t)col * LDIM + row0) = ph;
#pragma unroll
                for (int r = 0; r < 4; r++)
                    Pb[(size_t)(row0 + r) * LDIM + col] = ph[r];
                csum += (float)ph[0] + (float)ph[1] + (float)ph[2] + (float)ph[3];
            }
        }
        csum += __shfl_xor(csum, 16, 64);
        csum += __shfl_xor(csum, 32, 64);
        if (quad == 0 && col < LDIM) atomicAdd(Cb + col, csum);
    }
}

// ---- one Sinkhorn half-update (exp domain), one wave per row. ----
// first!=0: treat vin ≡ 1 (reference init u=v=0); capture interior row sums in Rcap.
// mscal!=null: also compute per-row max of cm = p*p/(mscal[row]*mvec[j]) -> mout
//              (bit-identical arithmetic to final_kernel for tie consistency).
__global__ __launch_bounds__(256) void skh_kernel(
    const _Float16* __restrict__ mat, const float* __restrict__ vin,
    float* __restrict__ vout, const float* __restrict__ alpha_p,
    float* __restrict__ Rcap, const float* __restrict__ mscal,
    const float* __restrict__ mvec, float* __restrict__ mout, int first)
{
    const int wave = threadIdx.x >> 6, lane = threadIdx.x & 63;
    const int row = blockIdx.x * 4 + wave, batch = blockIdx.y;
    if (row > LDIM) return;
    const float* vi = vin + batch * VS;
    float psum = 0.f, pmax = 0.f;
    if (row < LDIM) {
        const h8* m8 = (const h8*)(mat + ((size_t)batch * LDIM + row) * LDIM);
        const float4* b4 = (const float4*)vi;
        const float Rr = mscal ? mscal[batch * VS + row] : 0.f;
        const float4* c4 = mscal ? (const float4*)(mvec + batch * VS) : (const float4*)vi;
        for (int jv = lane; jv < 450; jv += 64) {
            h8 hv = m8[jv];
            float p0 = (float)hv[0], p1 = (float)hv[1], p2 = (float)hv[2], p3 = (float)hv[3];
            float p4 = (float)hv[4], p5 = (float)hv[5], p6 = (float)hv[6], p7 = (float)hv[7];
            if (first) {
                psum += (p0 + p1 + p2 + p3) + (p4 + p5 + p6 + p7);
            } else {
                float4 b0 = b4[2 * jv], b1 = b4[2 * jv + 1];
                psum += p0 * b0.x + p1 * b0.y + p2 * b0.z + p3 * b0.w;
                psum += p4 * b1.x + p5 * b1.y + p6 * b1.z + p7 * b1.w;
            }
            if (mscal) {
                float4 c0 = c4[2 * jv], c1 = c4[2 * jv + 1];
                pmax = fmaxf(pmax, (p0 * p0) / (Rr * c0.x));
                pmax = fmaxf(pmax, (p1 * p1) / (Rr * c0.y));
                pmax = fmaxf(pmax, (p2 * p2) / (Rr * c0.z));
                pmax = fmaxf(pmax, (p3 * p3) / (Rr * c0.w));
                pmax = fmaxf(pmax, (p4 * p4) / (Rr * c1.x));
                pmax = fmaxf(pmax, (p5 * p5) / (Rr * c1.y));
                pmax = fmaxf(pmax, (p6 * p6) / (Rr * c1.z));
                pmax = fmaxf(pmax, (p7 * p7) / (Rr * c1.w));
            }
        }
    } else {
        if (first) {
            if (lane == 0) psum = 3601.0f;   // 3600 interior + corner, all b=1
        } else {
            const float4* b4 = (const float4*)vi;
            for (int jv = lane; jv < 900; jv += 64) {
                float4 b0 = b4[jv];
                psum += (b0.x + b0.y) + (b0.z + b0.w);
            }
            if (lane == 0) psum += vi[LDIM];
        }
    }
#pragma unroll
    for (int off = 32; off; off >>= 1) {
        psum += __shfl_down(psum, off, 64);
        pmax = fmaxf(pmax, __shfl_down(pmax, off, 64));
    }
    if (lane == 0) {
        const float alpha = alpha_p[0];
        const float norm = -logf(7200.0f);
        float u;
        if (row < LDIM) {
            if (Rcap) Rcap[batch * VS + row] = psum;
            if (mout) mout[batch * VS + row] = pmax;
            float bc = first ? 1.0f : vi[LDIM];
            u = norm - __logf(psum + __expf(alpha) * bc);
        } else {
            u = (logf(3600.0f) + norm) - alpha - __logf(psum);
        }
        vout[batch * VS + row] = __expf(u);
    }
}

// ---- fused epilogue: cm, cf, conf_skh planes ----
__global__ __launch_bounds__(256) void final_kernel(
    const _Float16* __restrict__ P, const float* __restrict__ av, const float* __restrict__ bv,
    const float* __restrict__ Rvec, const float* __restrict__ Cvec,
    const float* __restrict__ rowM, const float* __restrict__ colM,
    float* __restrict__ out)
{
    const int batch = blockIdx.z, row = blockIdx.y;
    const int c0 = blockIdx.x * 1024 + threadIdx.x * 4;
    if (c0 >= LDIM) return;
    const _Float16* prow = P + ((size_t)batch * LDIM + row) * LDIM;
    h4v hv = *(const h4v*)(prow + c0);
    float4 bb = *(const float4*)(bv + batch * VS + c0);
    float4 cc = *(const float4*)(Cvec + batch * VS + c0);
    float4 cM = *(const float4*)(colM + batch * VS + c0);
    const float Rr = Rvec[batch * VS + row];
    const float rM = rowM[batch * VS + row];
    const float as = av[batch * VS + row] * 7200.0f;   // exp(u) * exp(-norm)

    float4 cmv, cfv, skv;
    {
        float p = (float)hv[0]; float cm = (p * p) / (Rr * cc.x);
        cmv.x = cm; cfv.x = (cm == rM && cm == cM.x) ? cm : 0.f; skv.x = p * as * bb.x;
    }
    {
        float p = (float)hv[1]; float cm = (p * p) / (Rr * cc.y);
        cmv.y = cm; cfv.y = (cm == rM && cm == cM.y) ? cm : 0.f; skv.y = p * as * bb.y;
    }
    {
        float p = (float)hv[2]; float cm = (p * p) / (Rr * cc.z);
        cmv.z = cm; cfv.z = (cm == rM && cm == cM.z) ? cm : 0.f; skv.z = p * as * bb.z;
    }
    {
        float p = (float)hv[3]; float cm = (p * p) / (Rr * cc.w);
        cmv.w = cm; cfv.w = (cm == rM && cm == cM.w) ? cm : 0.f; skv.w = p * as * bb.w;
    }
    size_t base = ((size_t)batch * LDIM + row) * LDIM + c0;
    const size_t PLANE = (size_t)BDIM * LDIM * LDIM;
    *(float4*)(out + base) = cmv;
    *(float4*)(out + PLANE + base) = cfv;
    *(float4*)(out + 2 * PLANE + base) = skv;
}

extern "C" void kernel_launch(void* const* d_in, const int* in_sizes, int n_in,
                              void* d_out, int out_size, void* d_ws, size_t ws_size,
                              hipStream_t stream)
{
    const float* m0 = (const float*)d_in[0];
    const float* m1 = (const float*)d_in[1];
    const float* alpha = (const float*)d_in[2];
    float* out = (float*)d_out;
    char* ws = (char*)d_ws;

    // ws layout (bytes), all 16B-aligned; total ~111.3 MB
    short* Qb = (short*)(ws);                         //  3,686,400  bf16 mdesc0
    short* Rb = (short*)(ws + 3686400);               //  3,686,400  bf16 mdesc1
    _Float16* P  = (_Float16*)(ws + 7372800);         // 51,840,000  exp(sim)
    _Float16* PT = (_Float16*)(ws + 59212800);        // 51,840,000  exp(sim)^T
    float* vec = (float*)(ws + 111052800);            // vectors, stride VS per batch
    float* av   = vec;                                // exp(u), 2*VS
    float* bv   = vec + 2 * VS;                       // exp(v)
    float* Rv   = vec + 4 * VS;                       // row sums of P (fp16-rounded)
    float* Cv   = vec + 6 * VS;                       // col sums of P (fp16-rounded)
    float* rowM = vec + 8 * VS;                       // rowwise max of cm
    float* colM = vec + 10 * VS;                      // colwise max of cm

    hipMemsetAsync(Cv, 0, 2 * VS * sizeof(float), stream);
    convert_kernel<<<1800, 256, 0, stream>>>((const float4*)m0, (const float4*)m1,
                                             (short4*)Qb, (short4*)Rb);
    exp_gemm_kernel<<<dim3(29, 29, 2), 256, 0, stream>>>(Qb, Rb, P, PT, Cv);

    // Sinkhorn, exp domain. Pass 1: b==1 analytically, captures Rv.
    skh_kernel<<<dim3(901, 2), 256, 0, stream>>>(P, av, av, alpha, Rv, nullptr, nullptr, nullptr, 1);
    skh_kernel<<<dim3(901, 2), 256, 0, stream>>>(PT, av, bv, alpha, nullptr, nullptr, nullptr, nullptr, 0);
    for (int t = 1; t < T_ITERS - 1; ++t) {
        skh_kernel<<<dim3(901, 2), 256, 0, stream>>>(P, bv, av, alpha, nullptr, nullptr, nullptr, nullptr, 0);
        skh_kernel<<<dim3(901, 2), 256, 0, stream>>>(PT, av, bv, alpha, nullptr, nullptr, nullptr, nullptr, 0);
    }
    // last iteration: fuse rowM (over P, cm=p^2/(Rv[row]*Cv[j])) and colM (over PT, cm=p^2/(Cv[row]*Rv[j]))
    skh_kernel<<<dim3(901, 2), 256, 0, stream>>>(P, bv, av, alpha, nullptr, Rv, Cv, rowM, 0);
    skh_kernel<<<dim3(901, 2), 256, 0, stream>>>(PT, av, bv, alpha, nullptr, Cv, Rv, colM, 0);

    final_kernel<<<dim3(4, 3600, 2), 256, 0, stream>>>(P, av, bv, Rv, Cv, rowM, colM, out);
}

// Round 3
// 485.293 us; speedup vs baseline: 2.0221x; 1.1854x over previous
//
#include <hip/hip_runtime.h>
#include <hip/hip_bf16.h>
#include <cmath>

// MatchingNet round 3: 5 matrix passes, 8 dispatches.
//  * P = exp(sim) in [0.986,1.014] (fp16, + transposed copy PT) from ONE MFMA GEMM
//    that also emits row sums Rv and col sums Cv via shuffle+atomics.
//  * Sinkhorn in exp domain. Hilbert diameter of the kernel matrix is only
//    2*log(1.014/0.986)=0.057 (bin rows/cols are constant -> cross-ratios cancel),
//    contraction ~0.014 per half-step: T=3 full iterations is 4+ orders below the
//    fp16 quantization floor (measured absmax 4.77e-7 identical for T=20/T=5).
//  * u1 analytic from Rv (b==1). colM fused into first PT pass (cm uses only Rv,Cv).
//    rowM + final u-update fused into final_kernel (block-per-row, 2-phase).
//  * cm tie consistency: identical IEEE expression everywhere; colM pass computes
//    the product commuted (bitwise-equal for fp multiply).

#define LDIM 3600
#define DDIM 256
#define BDIM 2
#define VS   3604      // per-batch vector stride (floats), 16B-aligned

typedef __attribute__((ext_vector_type(8))) short    bf16x8;
typedef __attribute__((ext_vector_type(4))) float    f32x4;
typedef __attribute__((ext_vector_type(8))) _Float16 h8;
typedef __attribute__((ext_vector_type(4))) _Float16 h4v;

__device__ __forceinline__ short f2bf(float f) {
    unsigned u = __float_as_uint(f);
    u += 0x7fffu + ((u >> 16) & 1u);   // RNE
    return (short)(u >> 16);
}

// ---- input fp32 -> bf16 conversion ----
__global__ __launch_bounds__(256) void convert_kernel(
    const float4* __restrict__ m0, const float4* __restrict__ m1,
    short4* __restrict__ q, short4* __restrict__ r)
{
    int i = blockIdx.x * 256 + threadIdx.x;   // 460800 float4 per tensor
    float4 a = m0[i]; float4 b = m1[i];
    short4 qa, rb;
    qa.x = f2bf(a.x); qa.y = f2bf(a.y); qa.z = f2bf(a.z); qa.w = f2bf(a.w);
    rb.x = f2bf(b.x); rb.y = f2bf(b.y); rb.z = f2bf(b.z); rb.w = f2bf(b.w);
    q[i] = qa; r[i] = rb;
}

// ---- P[i][j]=exp(dot/6553.6) fp16; writes P, PT, row sums Rv, col sums Cv ----
// block = 4 waves (2x2), wave = 64x64 tile = 4x4 MFMA 16x16x32_bf16 tiles.
__global__ __launch_bounds__(256) void exp_gemm_kernel(
    const short* __restrict__ Xb, const short* __restrict__ Yb,
    _Float16* __restrict__ Pout, _Float16* __restrict__ PTout,
    float* __restrict__ Rv, float* __restrict__ Cv)
{
    const int batch = blockIdx.z;
    const short* X = Xb + (size_t)batch * LDIM * DDIM;
    const short* Y = Yb + (size_t)batch * LDIM * DDIM;
    _Float16* Pb  = Pout  + (size_t)batch * LDIM * LDIM;
    _Float16* PTb = PTout + (size_t)batch * LDIM * LDIM;
    float* Rb_ = Rv + batch * VS;
    float* Cb_ = Cv + batch * VS;

    const int wave = threadIdx.x >> 6;
    const int lane = threadIdx.x & 63;
    const int wm = wave >> 1, wn = wave & 1;
    const int bm0 = blockIdx.y * 128 + wm * 64;
    const int bn0 = blockIdx.x * 128 + wn * 64;
    const int l16 = lane & 15, quad = lane >> 4;

    f32x4 acc[4][4];
#pragma unroll
    for (int s = 0; s < 4; s++)
#pragma unroll
        for (int t = 0; t < 4; t++) acc[s][t] = (f32x4){0.f, 0.f, 0.f, 0.f};

    const short* xr[4]; const short* yr[4];
#pragma unroll
    for (int s = 0; s < 4; s++) {
        int r = bm0 + s * 16 + l16; r = r < LDIM ? r : LDIM - 1;
        xr[s] = X + (size_t)r * DDIM;
        int c = bn0 + s * 16 + l16; c = c < LDIM ? c : LDIM - 1;
        yr[s] = Y + (size_t)c * DDIM;
    }
    for (int k0 = 0; k0 < DDIM; k0 += 32) {
        const int kk = k0 + quad * 8;     // A[m=lane&15][k=quad*8+j]
        bf16x8 af[4], bfr[4];
#pragma unroll
        for (int s = 0; s < 4; s++) {
            af[s]  = *(const bf16x8*)(xr[s] + kk);
            bfr[s] = *(const bf16x8*)(yr[s] + kk);
        }
#pragma unroll
        for (int s = 0; s < 4; s++)
#pragma unroll
            for (int t = 0; t < 4; t++)
                acc[s][t] = __builtin_amdgcn_mfma_f32_16x16x32_bf16(af[s], bfr[t], acc[s][t], 0, 0, 0);
    }
    const float inv = 1.0f / 6553.6f;
    float rs[4][4];   // [s][r] partial row sums (cols this lane touches)
#pragma unroll
    for (int s = 0; s < 4; s++)
#pragma unroll
        for (int r = 0; r < 4; r++) rs[s][r] = 0.f;

#pragma unroll
    for (int t = 0; t < 4; t++) {
        const int col = bn0 + t * 16 + l16;     // D: col=lane&15, row=quad*4+reg
        float csum = 0.f;
#pragma unroll
        for (int s = 0; s < 4; s++) {
            const int row0 = bm0 + s * 16 + quad * 4;
            h4v ph;
#pragma unroll
            for (int r = 0; r < 4; r++) ph[r] = (_Float16)__expf(acc[s][t][r] * inv);
            if (col < LDIM && row0 < LDIM) {
                *(h4v*)(PTb + (size_t)col * LDIM + row0) = ph;
#pragma unroll
                for (int r = 0; r < 4; r++) {
                    Pb[(size_t)(row0 + r) * LDIM + col] = ph[r];
                    float pf = (float)ph[r];
                    rs[s][r] += pf;
                    csum += pf;
                }
            }
        }
        csum += __shfl_xor(csum, 16, 64);
        csum += __shfl_xor(csum, 32, 64);
        if (quad == 0 && col < LDIM) atomicAdd(Cb_ + col, csum);
    }
    // row sums: reduce over the 16 lanes (l16) of each quad, then atomics
#pragma unroll
    for (int s = 0; s < 4; s++) {
        const int row0 = bm0 + s * 16 + quad * 4;
#pragma unroll
        for (int r = 0; r < 4; r++) {
            float v = rs[s][r];
            v += __shfl_xor(v, 1, 64);
            v += __shfl_xor(v, 2, 64);
            v += __shfl_xor(v, 4, 64);
            v += __shfl_xor(v, 8, 64);
            if (l16 == 0 && row0 < LDIM) atomicAdd(Rb_ + row0 + r, v);
        }
    }
}

// ---- u1 = norm - log(Rv + e^alpha) (b==1 analytic first half-iteration) ----
__global__ __launch_bounds__(256) void u1_kernel(
    const float* __restrict__ Rv, float* __restrict__ av,
    const float* __restrict__ alpha_p)
{
    const int i = blockIdx.x * 256 + threadIdx.x, batch = blockIdx.y;
    if (i > LDIM) return;
    const float alpha = alpha_p[0];
    const float norm = -logf(7200.0f);
    float u;
    if (i < LDIM) u = norm - __logf(Rv[batch * VS + i] + __expf(alpha));
    else          u = (logf(3600.0f) + norm) - alpha - __logf(3601.0f);
    av[batch * VS + i] = __expf(u);
}

// ---- one Sinkhorn half-update (exp domain), one wave per row. ----
// mscal!=null: also per-row max of cm = p*p/(mscal[row]*mvec[j]) -> mout
__global__ __launch_bounds__(256) void skh_kernel(
    const _Float16* __restrict__ mat, const float* __restrict__ vin,
    float* __restrict__ vout, const float* __restrict__ alpha_p,
    const float* __restrict__ mscal, const float* __restrict__ mvec,
    float* __restrict__ mout)
{
    const int wave = threadIdx.x >> 6, lane = threadIdx.x & 63;
    const int row = blockIdx.x * 4 + wave, batch = blockIdx.y;
    if (row > LDIM) return;
    const float* vi = vin + batch * VS;
    float psum = 0.f, pmax = 0.f;
    if (row < LDIM) {
        const h8* m8 = (const h8*)(mat + ((size_t)batch * LDIM + row) * LDIM);
        const float4* b4 = (const float4*)vi;
        const float Rr = mscal ? mscal[batch * VS + row] : 0.f;
        const float4* c4 = mscal ? (const float4*)(mvec + batch * VS) : (const float4*)vi;
        for (int jv = lane; jv < 450; jv += 64) {
            h8 hv = m8[jv];
            float p0 = (float)hv[0], p1 = (float)hv[1], p2 = (float)hv[2], p3 = (float)hv[3];
            float p4 = (float)hv[4], p5 = (float)hv[5], p6 = (float)hv[6], p7 = (float)hv[7];
            float4 b0 = b4[2 * jv], b1 = b4[2 * jv + 1];
            psum += p0 * b0.x + p1 * b0.y + p2 * b0.z + p3 * b0.w;
            psum += p4 * b1.x + p5 * b1.y + p6 * b1.z + p7 * b1.w;
            if (mscal) {
                float4 c0 = c4[2 * jv], c1 = c4[2 * jv + 1];
                pmax = fmaxf(pmax, (p0 * p0) / (Rr * c0.x));
                pmax = fmaxf(pmax, (p1 * p1) / (Rr * c0.y));
                pmax = fmaxf(pmax, (p2 * p2) / (Rr * c0.z));
                pmax = fmaxf(pmax, (p3 * p3) / (Rr * c0.w));
                pmax = fmaxf(pmax, (p4 * p4) / (Rr * c1.x));
                pmax = fmaxf(pmax, (p5 * p5) / (Rr * c1.y));
                pmax = fmaxf(pmax, (p6 * p6) / (Rr * c1.z));
                pmax = fmaxf(pmax, (p7 * p7) / (Rr * c1.w));
            }
        }
    } else {
        const float4* b4 = (const float4*)vi;
        for (int jv = lane; jv < 900; jv += 64) {
            float4 b0 = b4[jv];
            psum += (b0.x + b0.y) + (b0.z + b0.w);
        }
        if (lane == 0) psum += vi[LDIM];
    }
#pragma unroll
    for (int off = 32; off; off >>= 1) {
        psum += __shfl_down(psum, off, 64);
        pmax = fmaxf(pmax, __shfl_down(pmax, off, 64));
    }
    if (lane == 0) {
        const float alpha = alpha_p[0];
        const float norm = -logf(7200.0f);
        float u;
        if (row < LDIM) {
            if (mout) mout[batch * VS + row] = pmax;
            u = norm - __logf(psum + __expf(alpha) * vi[LDIM]);
        } else {
            u = (logf(3600.0f) + norm) - alpha - __logf(psum);
        }
        vout[batch * VS + row] = __expf(u);
    }
}

// ---- fused epilogue: final u-update + rowM + cm/cf/skh planes. Block per row. ----
__global__ __launch_bounds__(256) void final_kernel(
    const _Float16* __restrict__ P, const float* __restrict__ bv,
    const float* __restrict__ Rvec, const float* __restrict__ Cvec,
    const float* __restrict__ colM, const float* __restrict__ alpha_p,
    float* __restrict__ out)
{
    const int batch = blockIdx.y, row = blockIdx.x, tid = threadIdx.x;
    const h4v* prow = (const h4v*)(P + ((size_t)batch * LDIM + row) * LDIM);
    const float4* b4 = (const float4*)(bv + batch * VS);
    const float4* c4 = (const float4*)(Cvec + batch * VS);
    const float4* m4 = (const float4*)(colM + batch * VS);
    const float Rr = Rvec[batch * VS + row];

    // phase 1: row reduction -> psum (for u), pmax (rowM)
    float psum = 0.f, pmax = 0.f;
    for (int jv = tid; jv < 900; jv += 256) {
        h4v hv = prow[jv]; float4 b = b4[jv]; float4 c = c4[jv];
        float p0 = (float)hv[0], p1 = (float)hv[1], p2 = (float)hv[2], p3 = (float)hv[3];
        psum += p0 * b.x + p1 * b.y + p2 * b.z + p3 * b.w;
        pmax = fmaxf(pmax, (p0 * p0) / (Rr * c.x));
        pmax = fmaxf(pmax, (p1 * p1) / (Rr * c.y));
        pmax = fmaxf(pmax, (p2 * p2) / (Rr * c.z));
        pmax = fmaxf(pmax, (p3 * p3) / (Rr * c.w));
    }
    __shared__ float red_s[256], red_m[256];
    red_s[tid] = psum; red_m[tid] = pmax; __syncthreads();
    for (int w = 128; w; w >>= 1) {
        if (tid < w) {
            red_s[tid] += red_s[tid + w];
            red_m[tid] = fmaxf(red_m[tid], red_m[tid + w]);
        }
        __syncthreads();
    }
    __shared__ float s_as, s_rM;
    if (tid == 0) {
        const float alpha = alpha_p[0];
        const float norm = -logf(7200.0f);
        float u = norm - __logf(red_s[0] + __expf(alpha) * bv[batch * VS + LDIM]);
        s_as = __expf(u) * 7200.0f;
        s_rM = red_m[0];
    }
    __syncthreads();
    const float as = s_as, rM = s_rM;

    // phase 2: outputs (row data hot in L1)
    const size_t PLANE = (size_t)BDIM * LDIM * LDIM;
    const size_t base = ((size_t)batch * LDIM + row) * LDIM;
    for (int jv = tid; jv < 900; jv += 256) {
        h4v hv = prow[jv]; float4 b = b4[jv]; float4 c = c4[jv]; float4 cM = m4[jv];
        float4 cmv, cfv, skv;
        {
            float p = (float)hv[0]; float cm = (p * p) / (Rr * c.x);
            cmv.x = cm; cfv.x = (cm == rM && cm == cM.x) ? cm : 0.f; skv.x = p * as * b.x;
        }
        {
            float p = (float)hv[1]; float cm = (p * p) / (Rr * c.y);
            cmv.y = cm; cfv.y = (cm == rM && cm == cM.y) ? cm : 0.f; skv.y = p * as * b.y;
        }
        {
            float p = (float)hv[2]; float cm = (p * p) / (Rr * c.z);
            cmv.z = cm; cfv.z = (cm == rM && cm == cM.z) ? cm : 0.f; skv.z = p * as * b.z;
        }
        {
            float p = (float)hv[3]; float cm = (p * p) / (Rr * c.w);
            cmv.w = cm; cfv.w = (cm == rM && cm == cM.w) ? cm : 0.f; skv.w = p * as * b.w;
        }
        *(float4*)(out + base + jv * 4) = cmv;
        *(float4*)(out + PLANE + base + jv * 4) = cfv;
        *(float4*)(out + 2 * PLANE + base + jv * 4) = skv;
    }
}

extern "C" void kernel_launch(void* const* d_in, const int* in_sizes, int n_in,
                              void* d_out, int out_size, void* d_ws, size_t ws_size,
                              hipStream_t stream)
{
    const float* m0 = (const float*)d_in[0];
    const float* m1 = (const float*)d_in[1];
    const float* alpha = (const float*)d_in[2];
    float* out = (float*)d_out;
    char* ws = (char*)d_ws;

    // ws layout (bytes), all 16B-aligned; total ~111.3 MB
    short* Qb = (short*)(ws);                         //  3,686,400  bf16 mdesc0
    short* Rb = (short*)(ws + 3686400);               //  3,686,400  bf16 mdesc1
    _Float16* P  = (_Float16*)(ws + 7372800);         // 51,840,000  exp(sim)
    _Float16* PT = (_Float16*)(ws + 59212800);        // 51,840,000  exp(sim)^T
    float* vec = (float*)(ws + 111052800);            // vectors, stride VS per batch
    float* Rv   = vec;                                // row sums of P   [2*VS]
    float* Cv   = vec + 2 * VS;                       // col sums of P   [2*VS]
    float* av   = vec + 4 * VS;                       // exp(u)          [2*VS]
    float* bv   = vec + 6 * VS;                       // exp(v)          [2*VS]
    float* colM = vec + 8 * VS;                       // colwise max of cm

    hipMemsetAsync(Rv, 0, 4 * VS * sizeof(float), stream);   // Rv + Cv
    convert_kernel<<<1800, 256, 0, stream>>>((const float4*)m0, (const float4*)m1,
                                             (short4*)Qb, (short4*)Rb);
    exp_gemm_kernel<<<dim3(29, 29, 2), 256, 0, stream>>>(Qb, Rb, P, PT, Rv, Cv);

    // Sinkhorn T=3 (exp domain): u1 analytic from Rv; v1(+colM); u2; v2; u3 in final.
    u1_kernel<<<dim3(15, 2), 256, 0, stream>>>(Rv, av, alpha);
    skh_kernel<<<dim3(901, 2), 256, 0, stream>>>(PT, av, bv, alpha, Cv, Rv, colM);
    skh_kernel<<<dim3(901, 2), 256, 0, stream>>>(P, bv, av, alpha, nullptr, nullptr, nullptr);
    skh_kernel<<<dim3(901, 2), 256, 0, stream>>>(PT, av, bv, alpha, nullptr, nullptr, nullptr);

    final_kernel<<<dim3(3600, 2), 256, 0, stream>>>(P, bv, Rv, Cv, colM, alpha, out);
}